// Round 9
// baseline (105.437 us; speedup 1.0000x reference)
//
#include <hip/hip_runtime.h>
#include <hip/hip_bf16.h>
#include <stdint.h>

// S5 layer on MI355X — round 9:
//   gemm1  : round-8 K-loop + FUSED local-scan epilogue (tile == chunk):
//            acc -> LDS -> per-pole 64-step scan -> x~ (local prefix) to Vb bf16,
//            chunk-end states to E. scanA kernel deleted.
//   scanB  : exact shuffle-scan carry (unchanged).
//   scanC  : exact elementwise combine x = x~ + A^{tl+1}*carry -> Xb.
//   gemm23 : 128x256 tile, grid 512 (2 blocks/CU), 3-slot ring (72KB LDS),
//            counted vmcnt(3) (never 0 in loop), T2 swizzle, T5 setprio,
//            T1 XCD swizzle, LDS-transpose epilogue with dwordx4 C stores.

#define BATCH 8
#define SEQ   4096
#define DMODEL 512
#define HALF  64
#define CHUNK 64
#define NCHUNK (SEQ / CHUNK)   // 64

typedef __attribute__((ext_vector_type(8))) short short8;
typedef __attribute__((ext_vector_type(4))) float f32x4;

__device__ __forceinline__ unsigned short f2bf(float f) {
    unsigned int u = __float_as_uint(f);
    u += 0x7fffu + ((u >> 16) & 1u);
    return (unsigned short)(u >> 16);
}
__device__ __forceinline__ float bf2f(unsigned short s) {
    return __uint_as_float((unsigned)s << 16);
}

#define GLOAD_LDS16(g, l)                                                    \
    __builtin_amdgcn_global_load_lds(                                        \
        (const __attribute__((address_space(1))) unsigned int*)(g),          \
        (__attribute__((address_space(3))) unsigned int*)(l), 16, 0, 0)

// ---------------- precompute ----------------

__global__ void k_consts(const float* __restrict__ logLr,
                         const float* __restrict__ Li_in,
                         const float* __restrict__ logDelta,
                         float* __restrict__ sr, float* __restrict__ si,
                         float* __restrict__ ApR, float* __restrict__ ApI) {
    int n = threadIdx.x;  // 0..63
    float Delta = expf(logDelta[0]);
    float llr = fminf(fmaxf(logLr[n], -10.f), 10.f);
    float Lr = -expf(llr);
    float Li = Li_in[n];
    float dr = 1.f - 0.5f * Delta * Lr;
    float di = -0.5f * Delta * Li;
    float dn = dr * dr + di * di;
    float nr = 1.f + 0.5f * Delta * Lr;
    float ni = 0.5f * Delta * Li;
    float Ar = (nr * dr + ni * di) / dn;
    float Ai = (ni * dr - nr * di) / dn;
    sr[n] = Delta * dr / dn;
    si[n] = -Delta * di / dn;
    float pr = 1.f, pi = 0.f;
    for (int k = 0; k <= CHUNK; ++k) {
        ApR[k * HALF + n] = pr;
        ApI[k * HALF + n] = pi;
        float npr = pr * Ar - pi * Ai;
        float npi = pr * Ai + pi * Ar;
        pr = npr; pi = npi;
    }
}

__global__ void k_build_Mv(const float* __restrict__ Br, const float* __restrict__ Bi,
                           const float* __restrict__ sr, const float* __restrict__ si,
                           unsigned short* __restrict__ Mv) {
    int np = blockIdx.x, p = threadIdx.x;
    int n = np & 63;
    float br = Br[n * DMODEL + p], bi = Bi[n * DMODEL + p];
    float v = (np < HALF) ? (sr[n] * br - si[n] * bi)
                          : (si[n] * br + sr[n] * bi);
    Mv[np * DMODEL + p] = f2bf(v);
}

__global__ void k_build_W(const float* __restrict__ Cr, const float* __restrict__ Ci,
                          const float* __restrict__ D, unsigned short* __restrict__ W) {
    int p = blockIdx.x, j = threadIdx.x;
    float v;
    if (j < HALF) v = 2.f * Cr[p * HALF + j];
    else if (j < 2 * HALF) v = -2.f * Ci[p * HALF + (j - HALF)];
    else v = D[p * DMODEL + (j - 2 * HALF)];
    W[p * 640 + j] = f2bf(v);
}

// ---------------- GEMM1 + fused local scan ----------------
// 64x128 tile == one (b,chunk). K-loop: round-8 structure. Epilogue:
// acc -> Vt LDS -> 64-thread complex scan (x~ local prefix, E chunk-end)
// -> Vb bf16 (vectorized), E f32.
__global__ __launch_bounds__(512) void gemm1(const float* __restrict__ U,
                                             const unsigned short* __restrict__ Mv,
                                             unsigned short* __restrict__ Vb,
                                             unsigned short* __restrict__ Ub,
                                             const float* __restrict__ ApR,
                                             const float* __restrict__ ApI,
                                             float* __restrict__ E) {
    __shared__ __align__(16) unsigned short As[64 * 32];
    __shared__ __align__(16) unsigned short Bs[128 * 32];
    __shared__ __align__(16) float Vt[64 * 132];   // 33.8 KB, stride-132 pad
    const int tid = threadIdx.x;
    const int lane = tid & 63;
    const int w = tid >> 6;            // 0..7
    const int wm = w >> 2, wn = w & 3; // 2 x 4
    const int l15 = lane & 15, l4 = lane >> 4;
    const int row0 = blockIdx.x * 64;
    const int srow = tid >> 3;         // 0..63
    const int sh = (tid & 7) * 4;      // 0..28

    f32x4 acc[2][2];
#pragma unroll
    for (int m = 0; m < 2; ++m)
#pragma unroll
        for (int n = 0; n < 2; ++n) acc[m][n] = (f32x4)(0.f);

    for (int k0 = 0; k0 < DMODEL; k0 += 32) {
        const float4 av = *(const float4*)(U + (size_t)(row0 + srow) * DMODEL + k0 + sh);

        __syncthreads();   // prior tile's LDS reads complete

        GLOAD_LDS16(Mv + (size_t)(tid >> 2) * DMODEL + k0 + (tid & 3) * 8,
                    &Bs[(w * 64) * 8]);

        uint2 wa;
        wa.x = (unsigned)f2bf(av.x) | ((unsigned)f2bf(av.y) << 16);
        wa.y = (unsigned)f2bf(av.z) | ((unsigned)f2bf(av.w) << 16);
        *(uint2*)&As[srow * 32 + sh] = wa;
        *(uint2*)&Ub[(size_t)(row0 + srow) * DMODEL + k0 + sh] = wa;

        __syncthreads();   // vmcnt+lgkm drain: tiles staged

        short8 af[2], bf[2];
#pragma unroll
        for (int m = 0; m < 2; ++m)
            af[m] = *(const short8*)&As[(wm * 32 + m * 16 + l15) * 32 + l4 * 8];
#pragma unroll
        for (int n = 0; n < 2; ++n)
            bf[n] = *(const short8*)&Bs[(wn * 32 + n * 16 + l15) * 32 + l4 * 8];
#pragma unroll
        for (int m = 0; m < 2; ++m)
#pragma unroll
            for (int n = 0; n < 2; ++n)
                acc[m][n] = __builtin_amdgcn_mfma_f32_16x16x32_bf16(af[m], bf[n], acc[m][n], 0, 0, 0);
    }

    // ---- epilogue: acc -> Vt ----
    __syncthreads();
#pragma unroll
    for (int m = 0; m < 2; ++m)
#pragma unroll
        for (int n = 0; n < 2; ++n)
#pragma unroll
            for (int r = 0; r < 4; ++r)
                Vt[(wm * 32 + m * 16 + l4 * 4 + r) * 132 + wn * 32 + n * 16 + l15] = acc[m][n][r];
    __syncthreads();

    // ---- local complex scan over t (rows), in place: x~ inclusive prefix ----
    const int b = row0 >> 12;
    const int c = (row0 >> 6) & 63;
    if (tid < 64) {
        int n = tid;
        float Ar = ApR[HALF + n], Ai = ApI[HALF + n];
        float xr = 0.f, xi = 0.f;
        for (int tl = 0; tl < CHUNK; ++tl) {
            float vr = Vt[tl * 132 + n], vi = Vt[tl * 132 + 64 + n];
            float nxr = Ar * xr - Ai * xi + vr;
            float nxi = Ar * xi + Ai * xr + vi;
            xr = nxr; xi = nxi;
            Vt[tl * 132 + n] = xr; Vt[tl * 132 + 64 + n] = xi;
        }
        int ei = ((b * NCHUNK + c) * 2) * HALF + n;
        E[ei] = xr; E[ei + 64] = xi;
    }
    __syncthreads();

    // ---- Vt (x~) -> Vb bf16, vectorized ----
#pragma unroll
    for (int j = 0; j < 2; ++j) {
        int idx = tid * 2 + j;          // 0..1023
        int row = idx >> 4, oc = idx & 15;
        const float* vs = &Vt[row * 132 + oc * 8];
        uint4 pk;
        pk.x = (unsigned)f2bf(vs[0]) | ((unsigned)f2bf(vs[1]) << 16);
        pk.y = (unsigned)f2bf(vs[2]) | ((unsigned)f2bf(vs[3]) << 16);
        pk.z = (unsigned)f2bf(vs[4]) | ((unsigned)f2bf(vs[5]) << 16);
        pk.w = (unsigned)f2bf(vs[6]) | ((unsigned)f2bf(vs[7]) << 16);
        *(uint4*)&Vb[(size_t)(row0 + row) * 128 + oc * 8] = pk;
    }
}

// ---------------- scanB: exact carry prefix (unchanged) ----------------
__global__ void k_scanB(const float* __restrict__ E, float* __restrict__ Carry,
                        const float* __restrict__ ApR, const float* __restrict__ ApI) {
    int lane = threadIdx.x & 63;   // chunk c
    int wv = threadIdx.x >> 6;     // 0..7
    int b = blockIdx.x;
    for (int n = wv; n < HALF; n += 8) {
        float wr = ApR[CHUNK * HALF + n], wi = ApI[CHUNK * HALF + n];  // A^64
        int idx = ((b * NCHUNK + lane) * 2) * HALF + n;
        float sR = E[idx], sI = E[idx + 64];
#pragma unroll
        for (int s = 1; s < 64; s <<= 1) {
            float pR = __shfl_up(sR, s, 64);
            float pI = __shfl_up(sI, s, 64);
            if (lane >= s) {
                sR += wr * pR - wi * pI;
                sI += wr * pI + wi * pR;
            }
            float nwr = wr * wr - wi * wi;
            float nwi = 2.f * wr * wi;
            wr = nwr; wi = nwi;
        }
        float cR = __shfl_up(sR, 1, 64);
        float cI = __shfl_up(sI, 1, 64);
        if (lane == 0) { cR = 0.f; cI = 0.f; }
        Carry[idx] = cR; Carry[idx + 64] = cI;
    }
}

// ---------------- scanC: exact combine x = x~ + A^{tl+1}*carry ----------------
__global__ void k_scanC(const unsigned short* __restrict__ Vb,
                        const float* __restrict__ Carry,
                        const float* __restrict__ ApR, const float* __restrict__ ApI,
                        unsigned short* __restrict__ Xb) {
    int tid = threadIdx.x;
    int n = tid & 63;
    int c = ((blockIdx.x & 31) << 1) + (tid >> 6);
    int b = blockIdx.x >> 5;
    int cidx = ((b * NCHUNK + c) * 2) * HALF + n;
    float cr = Carry[cidx], ci = Carry[cidx + 64];
    size_t base = ((size_t)b * SEQ + (size_t)c * CHUNK) * 128 + n;
    for (int tl = 0; tl < CHUNK; ++tl) {
        float pr = ApR[(tl + 1) * HALF + n], pi = ApI[(tl + 1) * HALF + n];
        float xr = bf2f(Vb[base])      + pr * cr - pi * ci;
        float xi = bf2f(Vb[base + 64]) + pr * ci + pi * cr;
        Xb[base] = f2bf(xr); Xb[base + 64] = f2bf(xi);
        base += 128;
    }
}

// ---------------- GEMM23: out = [Xb | Ub] @ W^T ----------------
// 128x256 tile, BK=32/phase, 20 phases. 3-slot ring: A[3][128][32] @ 0,
// B[3][256][32] @ 12288 shorts; 72 KiB -> 2 blocks/CU. Counted vmcnt(3).
// 8 waves 2M x 4N, wave 64x64 (acc[4][4], 8 b128 ds_reads / phase).
// Epilogue: LDS transpose (reuse ring LDS) -> dwordx4 coalesced C stores.

#define STAGE_P(p) do {                                                        \
    const int kb_ = ((p) >> 1) * 64 + ((p) & 1) * 32;                          \
    { int c_ = tid; int ct_ = c_ ^ (((c_ >> 5) & 1) << 1);                     \
      int r_ = ct_ >> 2; int kc_ = kb_ + (ct_ & 3) * 8;                        \
      const unsigned short* s_ = (kc_ < 128)                                   \
          ? Xb + (size_t)(row0 + r_) * 128 + kc_                               \
          : Ub + (size_t)(row0 + r_) * 512 + (kc_ - 128);                      \
      GLOAD_LDS16(s_, &lds[((p) % 3) * 4096 + (w * 64) * 8]); }                \
    _Pragma("unroll") for (int j_ = 0; j_ < 2; ++j_) {                         \
      int c_ = j_ * 512 + tid; int ct_ = c_ ^ (((c_ >> 5) & 1) << 1);          \
      int r_ = ct_ >> 2; int kc_ = kb_ + (ct_ & 3) * 8;                        \
      GLOAD_LDS16(W + (size_t)(col0 + r_) * 640 + kc_,                         \
                  &lds[12288 + ((p) % 3) * 8192 + (j_ * 512 + w * 64) * 8]);   \
    } } while (0)

#define LDAB_P(p) do {                                                         \
    _Pragma("unroll") for (int i_ = 0; i_ < 4; ++i_) {                         \
        int r_ = wm * 64 + i_ * 16 + l15;                                      \
        int c_ = (l4 * 8) ^ (((r_ >> 3) & 1) << 4);                            \
        af[i_] = *(const short8*)&lds[((p) % 3) * 4096 + r_ * 32 + c_]; }      \
    _Pragma("unroll") for (int j_ = 0; j_ < 4; ++j_) {                         \
        int r_ = wn * 64 + j_ * 16 + l15;                                      \
        int c_ = (l4 * 8) ^ (((r_ >> 3) & 1) << 4);                            \
        bf[j_] = *(const short8*)&lds[12288 + ((p) % 3) * 8192 + r_ * 32 + c_]; } \
    } while (0)

#define MFMA16() do {                                                          \
    __builtin_amdgcn_s_setprio(1);                                             \
    _Pragma("unroll") for (int i_ = 0; i_ < 4; ++i_)                           \
    _Pragma("unroll") for (int j_ = 0; j_ < 4; ++j_)                           \
        acc[i_][j_] = __builtin_amdgcn_mfma_f32_16x16x32_bf16(                 \
            af[i_], bf[j_], acc[i_][j_], 0, 0, 0);                             \
    __builtin_amdgcn_s_setprio(0);                                             \
} while (0)

__global__ __launch_bounds__(512) void gemm23_r(const unsigned short* __restrict__ Xb,
                                                const unsigned short* __restrict__ Ub,
                                                const unsigned short* __restrict__ W,
                                                float* __restrict__ C) {
    __shared__ __align__(16) unsigned short lds[36864];  // 72 KiB
    const int tid = threadIdx.x;
    const int lane = tid & 63;
    const int w = tid >> 6;             // 0..7
    const int wm = w >> 2, wn = w & 3;  // 2 x 4 over 128x256
    const int l15 = lane & 15, l4 = lane >> 4;

    // T1: bijective XCD swizzle over 512 blocks (512 % 8 == 0)
    int lin = blockIdx.y * gridDim.x + blockIdx.x;  // 0..511
    int sw = (lin & 7) * 64 + (lin >> 3);
    const int row0 = (sw & 255) * 128;
    const int col0 = (sw >> 8) * 256;

    f32x4 acc[4][4];
#pragma unroll
    for (int m = 0; m < 4; ++m)
#pragma unroll
        for (int n = 0; n < 4; ++n) acc[m][n] = (f32x4)(0.f);

    // prologue: stage phases 0,1 (6 loads/thread... 3 per phase)
    STAGE_P(0);
    STAGE_P(1);

    short8 af[4], bf[4];
#pragma unroll
    for (int p = 0; p < 19; ++p) {
        asm volatile("s_waitcnt vmcnt(3)" ::: "memory");   // phase p staged
        __builtin_amdgcn_s_barrier();
        __builtin_amdgcn_sched_barrier(0);
        LDAB_P(p);
        if (p < 18) STAGE_P(p + 2);
        MFMA16();
    }
    asm volatile("s_waitcnt vmcnt(0)" ::: "memory");
    __builtin_amdgcn_s_barrier();
    __builtin_amdgcn_sched_barrier(0);
    LDAB_P(19);
    MFMA16();

    // ---- epilogue: LDS transpose -> coalesced dwordx4 stores ----
    float* lf = (float*)lds;   // 32 x 264 f32 region (33.8 KB of 72)
#pragma unroll
    for (int i = 0; i < 4; ++i) {
        __syncthreads();
#pragma unroll
        for (int j = 0; j < 4; ++j)
#pragma unroll
            for (int r = 0; r < 4; ++r)
                lf[(wm * 16 + l4 * 4 + r) * 264 + wn * 64 + j * 16 + l15] = acc[i][j][r];
        __syncthreads();
        {
            int rr = tid >> 4;           // 0..31
            int cg = tid & 15;           // 0..15
            int gr = row0 + (rr >> 4) * 64 + i * 16 + (rr & 15);
            float* cp = &C[(size_t)gr * DMODEL + col0 + cg * 16];
            const float* ls = &lf[rr * 264 + cg * 16];
#pragma unroll
            for (int j = 0; j < 4; ++j)
                *(float4*)(cp + j * 4) = *(const float4*)(ls + j * 4);
        }
    }
}

// ---------------- launch ----------------

extern "C" void kernel_launch(void* const* d_in, const int* in_sizes, int n_in,
                              void* d_out, int out_size, void* d_ws, size_t ws_size,
                              hipStream_t stream) {
    const float* u      = (const float*)d_in[0];
    const float* logLr  = (const float*)d_in[1];
    const float* Li     = (const float*)d_in[2];
    const float* Br     = (const float*)d_in[3];
    const float* Bi     = (const float*)d_in[4];
    const float* Cr     = (const float*)d_in[5];
    const float* Ci     = (const float*)d_in[6];
    const float* D      = (const float*)d_in[7];
    const float* logDel = (const float*)d_in[8];
    float* out = (float*)d_out;

    const size_t M = (size_t)BATCH * SEQ;  // 32768
    unsigned short* Vb = (unsigned short*)d_ws;       // M*128 (holds x~)
    unsigned short* Ub = Vb + M * 128;                // M*512
    unsigned short* Xb = Ub + M * 512;                // M*128
    unsigned short* Mv = Xb + M * 128;                // 128*512
    unsigned short* W  = Mv + 128 * 512;              // 512*640
    float* fp    = (float*)(W + 512 * 640);
    float* E     = fp;                     // 65536
    float* Carry = E + 65536;              // 65536
    float* ApR   = Carry + 65536;          // 4160
    float* ApI   = ApR + 4160;             // 4160
    float* sr    = ApI + 4160;             // 64
    float* si    = sr + 64;                // 64

    hipLaunchKernelGGL(k_consts, dim3(1), dim3(64), 0, stream,
                       logLr, Li, logDel, sr, si, ApR, ApI);
    hipLaunchKernelGGL(k_build_Mv, dim3(128), dim3(512), 0, stream, Br, Bi, sr, si, Mv);
    hipLaunchKernelGGL(k_build_W, dim3(512), dim3(640), 0, stream, Cr, Ci, D, W);

    // GEMM1 + fused local scan: Vb = x~ (bf16), Ub = bf16(U), E = chunk ends
    hipLaunchKernelGGL(gemm1, dim3(M / 64), dim3(512), 0, stream,
                       u, Mv, Vb, Ub, ApR, ApI, E);

    // exact carry prefix, then elementwise combine -> Xb
    hipLaunchKernelGGL(k_scanB, dim3(BATCH), dim3(512), 0, stream, E, Carry, ApR, ApI);
    hipLaunchKernelGGL(k_scanC, dim3(256), dim3(128), 0, stream, Vb, Carry, ApR, ApI, Xb);

    // GEMM23: out = [Xb | Ub] @ W^T
    hipLaunchKernelGGL(gemm23_r, dim3(M / 128, DMODEL / 256), dim3(512), 0, stream,
                       Xb, Ub, W, out);
}

// Round 10
// 92.425 us; speedup vs baseline: 1.1408x; 1.1408x over previous
//
#include <hip/hip_runtime.h>
#include <hip/hip_bf16.h>
#include <stdint.h>

// S5 layer on MI355X — round 10: revert to round-8 base; single change:
//   gemm23 : 256x256, BK=32/kh-phase, 2-slot ring (64 KiB LDS -> 2 blocks/CU),
//            distance-1 prefetch (stage p+1 right after barrier p), vmcnt(0)
//            drain hidden by co-resident block (m114 overlap). T2 swizzle,
//            T5 setprio, T1 XCD swizzle kept.

#define BATCH 8
#define SEQ   4096
#define DMODEL 512
#define HALF  64
#define CHUNK 64
#define NCHUNK (SEQ / CHUNK)   // 64
#define NPH   20               // 640/32 kh-phases in gemm23

typedef __attribute__((ext_vector_type(8))) short short8;
typedef __attribute__((ext_vector_type(4))) float f32x4;

__device__ __forceinline__ unsigned short f2bf(float f) {
    unsigned int u = __float_as_uint(f);
    u += 0x7fffu + ((u >> 16) & 1u);
    return (unsigned short)(u >> 16);
}
__device__ __forceinline__ float bf2f(unsigned short s) {
    return __uint_as_float((unsigned)s << 16);
}

#define GLOAD_LDS16(g, l)                                                    \
    __builtin_amdgcn_global_load_lds(                                        \
        (const __attribute__((address_space(1))) unsigned int*)(g),          \
        (__attribute__((address_space(3))) unsigned int*)(l), 16, 0, 0)

// ---------------- precompute ----------------

__global__ void k_consts(const float* __restrict__ logLr,
                         const float* __restrict__ Li_in,
                         const float* __restrict__ logDelta,
                         float* __restrict__ sr, float* __restrict__ si,
                         float* __restrict__ ApR, float* __restrict__ ApI) {
    int n = threadIdx.x;  // 0..63
    float Delta = expf(logDelta[0]);
    float llr = fminf(fmaxf(logLr[n], -10.f), 10.f);
    float Lr = -expf(llr);
    float Li = Li_in[n];
    float dr = 1.f - 0.5f * Delta * Lr;
    float di = -0.5f * Delta * Li;
    float dn = dr * dr + di * di;
    float nr = 1.f + 0.5f * Delta * Lr;
    float ni = 0.5f * Delta * Li;
    float Ar = (nr * dr + ni * di) / dn;
    float Ai = (ni * dr - nr * di) / dn;
    sr[n] = Delta * dr / dn;
    si[n] = -Delta * di / dn;
    float pr = 1.f, pi = 0.f;
    for (int k = 0; k <= CHUNK; ++k) {
        ApR[k * HALF + n] = pr;
        ApI[k * HALF + n] = pi;
        float npr = pr * Ar - pi * Ai;
        float npi = pr * Ai + pi * Ar;
        pr = npr; pi = npi;
    }
}

__global__ void k_build_Mv(const float* __restrict__ Br, const float* __restrict__ Bi,
                           const float* __restrict__ sr, const float* __restrict__ si,
                           unsigned short* __restrict__ Mv) {
    int np = blockIdx.x, p = threadIdx.x;
    int n = np & 63;
    float br = Br[n * DMODEL + p], bi = Bi[n * DMODEL + p];
    float v = (np < HALF) ? (sr[n] * br - si[n] * bi)
                          : (si[n] * br + sr[n] * bi);
    Mv[np * DMODEL + p] = f2bf(v);
}

__global__ void k_build_W(const float* __restrict__ Cr, const float* __restrict__ Ci,
                          const float* __restrict__ D, unsigned short* __restrict__ W) {
    int p = blockIdx.x, j = threadIdx.x;
    float v;
    if (j < HALF) v = 2.f * Cr[p * HALF + j];
    else if (j < 2 * HALF) v = -2.f * Ci[p * HALF + (j - HALF)];
    else v = D[p * DMODEL + (j - 2 * HALF)];
    W[p * 640 + j] = f2bf(v);
}

// ---------------- scan (exact; V in bf16) ----------------

__global__ void k_scanA(const unsigned short* __restrict__ Vb,
                        const float* __restrict__ ApR, const float* __restrict__ ApI,
                        float* __restrict__ E) {
    int tid = threadIdx.x;
    int n = tid & 63;
    int c = ((blockIdx.x & 31) << 1) + (tid >> 6);
    int b = blockIdx.x >> 5;
    float Ar = ApR[HALF + n], Ai = ApI[HALF + n];
    float xr = 0.f, xi = 0.f;
    size_t base = ((size_t)b * SEQ + (size_t)c * CHUNK) * 128 + n;
    for (int tl = 0; tl < CHUNK; ++tl) {
        float vr = bf2f(Vb[base]), vi = bf2f(Vb[base + 64]);
        float nxr = Ar * xr - Ai * xi + vr;
        float nxi = Ar * xi + Ai * xr + vi;
        xr = nxr; xi = nxi;
        base += 128;
    }
    int eidx = ((b * NCHUNK + c) * 2) * HALF + n;
    E[eidx] = xr; E[eidx + 64] = xi;
}

__global__ void k_scanB(const float* __restrict__ E, float* __restrict__ Carry,
                        const float* __restrict__ ApR, const float* __restrict__ ApI) {
    int lane = threadIdx.x & 63;   // chunk c
    int wv = threadIdx.x >> 6;     // 0..7
    int b = blockIdx.x;
    for (int n = wv; n < HALF; n += 8) {
        float wr = ApR[CHUNK * HALF + n], wi = ApI[CHUNK * HALF + n];  // A^64
        int idx = ((b * NCHUNK + lane) * 2) * HALF + n;
        float sR = E[idx], sI = E[idx + 64];
#pragma unroll
        for (int s = 1; s < 64; s <<= 1) {
            float pR = __shfl_up(sR, s, 64);
            float pI = __shfl_up(sI, s, 64);
            if (lane >= s) {
                sR += wr * pR - wi * pI;
                sI += wr * pI + wi * pR;
            }
            float nwr = wr * wr - wi * wi;
            float nwi = 2.f * wr * wi;
            wr = nwr; wi = nwi;
        }
        float cR = __shfl_up(sR, 1, 64);
        float cI = __shfl_up(sI, 1, 64);
        if (lane == 0) { cR = 0.f; cI = 0.f; }
        Carry[idx] = cR; Carry[idx + 64] = cI;
    }
}

__global__ void k_scanC(const unsigned short* __restrict__ Vb,
                        const float* __restrict__ Carry,
                        const float* __restrict__ ApR, const float* __restrict__ ApI,
                        unsigned short* __restrict__ Xb) {
    int tid = threadIdx.x;
    int n = tid & 63;
    int c = ((blockIdx.x & 31) << 1) + (tid >> 6);
    int b = blockIdx.x >> 5;
    int cidx = ((b * NCHUNK + c) * 2) * HALF + n;
    float xr = Carry[cidx], xi = Carry[cidx + 64];
    float Ar = ApR[HALF + n], Ai = ApI[HALF + n];
    size_t base = ((size_t)b * SEQ + (size_t)c * CHUNK) * 128 + n;
    for (int tl = 0; tl < CHUNK; ++tl) {
        float vr = bf2f(Vb[base]), vi = bf2f(Vb[base + 64]);
        float nxr = Ar * xr - Ai * xi + vr;
        float nxi = Ar * xi + Ai * xr + vi;
        xr = nxr; xi = nxi;
        Xb[base] = f2bf(xr); Xb[base + 64] = f2bf(xi);
        base += 128;
    }
}

// ---------------- GEMM1: Vb = bf16(U @ Mv^T), Ub = bf16(U) ----------------
// 64x128 tile, 512 thr = 8 waves (2M x 4N), wave 32x32 (acc[2][2]).
// grid M/64 = 512 -> ~4 blocks/CU (12.25KB LDS), high TLP for memory-bound.
__global__ __launch_bounds__(512) void gemm1(const float* __restrict__ U,
                                             const unsigned short* __restrict__ Mv,
                                             unsigned short* __restrict__ Vb,
                                             unsigned short* __restrict__ Ub) {
    __shared__ __align__(16) unsigned short As[64 * 32];
    __shared__ __align__(16) unsigned short Bs[128 * 32];
    const int tid = threadIdx.x;
    const int lane = tid & 63;
    const int w = tid >> 6;            // 0..7
    const int wm = w >> 2, wn = w & 3; // 2 x 4
    const int l15 = lane & 15, l4 = lane >> 4;
    const int row0 = blockIdx.x * 64;
    const int srow = tid >> 3;         // 0..63
    const int sh = (tid & 7) * 4;      // 0..28

    f32x4 acc[2][2];
#pragma unroll
    for (int m = 0; m < 2; ++m)
#pragma unroll
        for (int n = 0; n < 2; ++n) acc[m][n] = (f32x4)(0.f);

    for (int k0 = 0; k0 < DMODEL; k0 += 32) {
        const float4 av = *(const float4*)(U + (size_t)(row0 + srow) * DMODEL + k0 + sh);

        __syncthreads();   // prior tile's LDS reads complete

        GLOAD_LDS16(Mv + (size_t)(tid >> 2) * DMODEL + k0 + (tid & 3) * 8,
                    &Bs[(w * 64) * 8]);

        uint2 wa;
        wa.x = (unsigned)f2bf(av.x) | ((unsigned)f2bf(av.y) << 16);
        wa.y = (unsigned)f2bf(av.z) | ((unsigned)f2bf(av.w) << 16);
        *(uint2*)&As[srow * 32 + sh] = wa;
        *(uint2*)&Ub[(size_t)(row0 + srow) * DMODEL + k0 + sh] = wa;

        __syncthreads();   // vmcnt+lgkm drain: tiles staged

        short8 af[2], bf[2];
#pragma unroll
        for (int m = 0; m < 2; ++m)
            af[m] = *(const short8*)&As[(wm * 32 + m * 16 + l15) * 32 + l4 * 8];
#pragma unroll
        for (int n = 0; n < 2; ++n)
            bf[n] = *(const short8*)&Bs[(wn * 32 + n * 16 + l15) * 32 + l4 * 8];
#pragma unroll
        for (int m = 0; m < 2; ++m)
#pragma unroll
            for (int n = 0; n < 2; ++n)
                acc[m][n] = __builtin_amdgcn_mfma_f32_16x16x32_bf16(af[m], bf[n], acc[m][n], 0, 0, 0);
    }

#pragma unroll
    for (int m = 0; m < 2; ++m) {
        int rbase = row0 + wm * 32 + m * 16 + l4 * 4;
#pragma unroll
        for (int n = 0; n < 2; ++n) {
            int col = wn * 32 + n * 16 + l15;
#pragma unroll
            for (int r = 0; r < 4; ++r)
                Vb[(size_t)(rbase + r) * 128 + col] = f2bf(acc[m][n][r]);
        }
    }
}

// ---------------- GEMM23: out = [Xb | Ub] @ W^T ----------------
// 256x256, BK=32 per kh-phase, NPH=20 phases. 2-slot ring: slot = p&1,
// A 16KB + B 16KB per slot = 64 KiB total -> 2 blocks/CU.
// Phase p: vmcnt(0) [STAGE(p) done]; barrier [slot (p+1)&1 readers done];
// STAGE(p+1) [other slot]; LDAB(p); MFMA32. Drain hidden by second block.

#define STAGE_P(p) do {                                                        \
    const int t_ = (p) >> 1, kh_ = (p) & 1, s_ = (p) & 1;                      \
    _Pragma("unroll") for (int j_ = 0; j_ < 2; ++j_) {                         \
        int c_ = j_ * 512 + tid;                                               \
        int ct_ = c_ ^ (((c_ >> 5) & 1) << 1);                                 \
        int r_ = (ct_ >> 2) & 255;                                             \
        int kcol_ = t_ * 64 + kh_ * 32 + (ct_ & 3) * 8;                        \
        const unsigned short* asrc_ = (kcol_ < 128)                            \
            ? Xb + (size_t)(row0 + r_) * 128 + kcol_                           \
            : Ub + (size_t)(row0 + r_) * 512 + (kcol_ - 128);                  \
        GLOAD_LDS16(asrc_, &As[s_ * 8192 + (j_ * 512 + w * 64) * 8]);          \
        GLOAD_LDS16(W + (size_t)(col0 + r_) * 640 + kcol_,                     \
                    &Bs[s_ * 8192 + (j_ * 512 + w * 64) * 8]);                 \
    } } while (0)

#define LDAB_P(p) do {                                                         \
    const int s_ = (p) & 1;                                                    \
    _Pragma("unroll") for (int i_ = 0; i_ < 8; ++i_) {                         \
        int r_ = wm * 128 + i_ * 16 + l15;                                     \
        int c_ = (l4 * 8) ^ (((r_ >> 3) & 1) << 4);                            \
        af[i_] = *(const short8*)&As[s_ * 8192 + r_ * 32 + c_]; }              \
    _Pragma("unroll") for (int j_ = 0; j_ < 4; ++j_) {                         \
        int r_ = wn * 64 + j_ * 16 + l15;                                      \
        int c_ = (l4 * 8) ^ (((r_ >> 3) & 1) << 4);                            \
        bf[j_] = *(const short8*)&Bs[s_ * 8192 + r_ * 32 + c_]; }              \
    } while (0)

#define MFMA32() do {                                                          \
    __builtin_amdgcn_s_setprio(1);                                             \
    _Pragma("unroll") for (int i_ = 0; i_ < 8; ++i_)                           \
    _Pragma("unroll") for (int j_ = 0; j_ < 4; ++j_)                           \
        acc[i_][j_] = __builtin_amdgcn_mfma_f32_16x16x32_bf16(                 \
            af[i_], bf[j_], acc[i_][j_], 0, 0, 0);                             \
    __builtin_amdgcn_s_setprio(0);                                             \
} while (0)

__global__ __launch_bounds__(512) void gemm23_2s(const unsigned short* __restrict__ Xb,
                                                 const unsigned short* __restrict__ Ub,
                                                 const unsigned short* __restrict__ W,
                                                 float* __restrict__ C) {
    __shared__ __align__(16) unsigned short As[2 * 8192];  // 32 KiB
    __shared__ __align__(16) unsigned short Bs[2 * 8192];  // 32 KiB
    const int tid = threadIdx.x;
    const int lane = tid & 63;
    const int w = tid >> 6;             // 0..7
    const int wm = w >> 2, wn = w & 3;  // 2 x 4
    const int l15 = lane & 15, l4 = lane >> 4;

    // T1: bijective XCD swizzle over 256 blocks
    int lin = blockIdx.y * gridDim.x + blockIdx.x;  // 0..255
    int sw = (lin & 7) * 32 + (lin >> 3);
    const int row0 = (sw & 127) * 256;
    const int col0 = (sw >> 7) * 256;

    f32x4 acc[8][4];
#pragma unroll
    for (int m = 0; m < 8; ++m)
#pragma unroll
        for (int n = 0; n < 4; ++n) acc[m][n] = (f32x4)(0.f);

    // prologue: stage phase 0 (4 loads/thread)
    STAGE_P(0);

    short8 af[8], bf[4];
#pragma unroll 2
    for (int p = 0; p < NPH; ++p) {
        asm volatile("s_waitcnt vmcnt(0)" ::: "memory");   // STAGE(p) complete
        __builtin_amdgcn_s_barrier();                      // slot (p+1)&1 readers done
        __builtin_amdgcn_sched_barrier(0);
        if (p < NPH - 1) STAGE_P(p + 1);                   // max issue-to-wait gap
        LDAB_P(p);
        MFMA32();
    }

#pragma unroll
    for (int m = 0; m < 8; ++m) {
        int rbase = row0 + wm * 128 + m * 16 + l4 * 4;
#pragma unroll
        for (int n = 0; n < 4; ++n) {
            int col = col0 + wn * 64 + n * 16 + l15;
#pragma unroll
            for (int r = 0; r < 4; ++r)
                C[(size_t)(rbase + r) * DMODEL + col] = acc[m][n][r];
        }
    }
}

// ---------------- launch ----------------

extern "C" void kernel_launch(void* const* d_in, const int* in_sizes, int n_in,
                              void* d_out, int out_size, void* d_ws, size_t ws_size,
                              hipStream_t stream) {
    const float* u      = (const float*)d_in[0];
    const float* logLr  = (const float*)d_in[1];
    const float* Li     = (const float*)d_in[2];
    const float* Br     = (const float*)d_in[3];
    const float* Bi     = (const float*)d_in[4];
    const float* Cr     = (const float*)d_in[5];
    const float* Ci     = (const float*)d_in[6];
    const float* D      = (const float*)d_in[7];
    const float* logDel = (const float*)d_in[8];
    float* out = (float*)d_out;

    const size_t M = (size_t)BATCH * SEQ;  // 32768
    unsigned short* Vb = (unsigned short*)d_ws;       // M*128
    unsigned short* Ub = Vb + M * 128;                // M*512
    unsigned short* Xb = Ub + M * 512;                // M*128
    unsigned short* Mv = Xb + M * 128;                // 128*512
    unsigned short* W  = Mv + 128 * 512;              // 512*640
    float* fp    = (float*)(W + 512 * 640);
    float* E     = fp;                     // 65536
    float* Carry = E + 65536;              // 65536
    float* ApR   = Carry + 65536;          // 4160
    float* ApI   = ApR + 4160;             // 4160
    float* sr    = ApI + 4160;             // 64
    float* si    = sr + 64;                // 64

    hipLaunchKernelGGL(k_consts, dim3(1), dim3(64), 0, stream,
                       logLr, Li, logDel, sr, si, ApR, ApI);
    hipLaunchKernelGGL(k_build_Mv, dim3(128), dim3(512), 0, stream, Br, Bi, sr, si, Mv);
    hipLaunchKernelGGL(k_build_W, dim3(512), dim3(640), 0, stream, Cr, Ci, D, W);

    // GEMM1: Vb = bf16(U @ Mv^T), Ub = bf16(U)
    hipLaunchKernelGGL(gemm1, dim3(M / 64), dim3(512), 0, stream, u, Mv, Vb, Ub);

    // scan: chunk-end states -> exact shuffle-scan carry -> seeded recurrence
    hipLaunchKernelGGL(k_scanA, dim3(256), dim3(128), 0, stream, Vb, ApR, ApI, E);
    hipLaunchKernelGGL(k_scanB, dim3(BATCH), dim3(512), 0, stream, E, Carry, ApR, ApI);
    hipLaunchKernelGGL(k_scanC, dim3(256), dim3(128), 0, stream, Vb, Carry, ApR, ApI, Xb);

    // GEMM23: out = [Xb | Ub] @ W^T
    hipLaunchKernelGGL(gemm23_2s, dim3(M / 256, DMODEL / 256), dim3(512), 0, stream,
                       Xb, Ub, W, out);
}

// Round 11
// 79.389 us; speedup vs baseline: 1.3281x; 1.1642x over previous
//
#include <hip/hip_runtime.h>
#include <hip/hip_bf16.h>
#include <stdint.h>

// S5 layer on MI355X — round 11: revert gemm23/gemm1 to round-8 (proven best);
// cut launch count 7 -> 5 and kill the serial scanB:
//   k_build : fused Mv + W build, sr/si computed inline (k_consts deleted)
//   gemm1   : r8 exact — 64x128 tile, 8 waves, gload_lds B, Vb/Ub bf16 out
//   scanA   : chunk-end states E; A computed per-thread (no table)
//   scanCB  : carry_c = sum_{jj} (A^64)^{jj-1} E_{c-jj} (exact, no serial phase)
//             then seeded recurrence -> Xb
//   gemm23  : r8 exact — 256x256, 4-slot kh ring (128 KiB), dist-3 prefetch,
//             counted vmcnt(8), T2 swizzle, T5 setprio, T1 XCD swizzle

#define BATCH 8
#define SEQ   4096
#define DMODEL 512
#define HALF  64
#define CHUNK 64
#define NCHUNK (SEQ / CHUNK)   // 64
#define NT    10               // 640/64 K-tiles in gemm23 (20 kh-phases)

typedef __attribute__((ext_vector_type(8))) short short8;
typedef __attribute__((ext_vector_type(4))) float f32x4;

__device__ __forceinline__ unsigned short f2bf(float f) {
    unsigned int u = __float_as_uint(f);
    u += 0x7fffu + ((u >> 16) & 1u);
    return (unsigned short)(u >> 16);
}
__device__ __forceinline__ float bf2f(unsigned short s) {
    return __uint_as_float((unsigned)s << 16);
}

// per-thread bilinear A for pole n (replaces the k_consts table)
__device__ __forceinline__ void poleA(const float* logLr, const float* Li_in,
                                      const float* logDelta, int n,
                                      float& Ar, float& Ai) {
    float Delta = expf(logDelta[0]);
    float llr = fminf(fmaxf(logLr[n], -10.f), 10.f);
    float Lr = -expf(llr);
    float Li = Li_in[n];
    float dr = 1.f - 0.5f * Delta * Lr;
    float di = -0.5f * Delta * Li;
    float dn = dr * dr + di * di;
    float nr = 1.f + 0.5f * Delta * Lr;
    float ni = 0.5f * Delta * Li;
    Ar = (nr * dr + ni * di) / dn;
    Ai = (ni * dr - nr * di) / dn;
}

#define GLOAD_LDS16(g, l)                                                    \
    __builtin_amdgcn_global_load_lds(                                        \
        (const __attribute__((address_space(1))) unsigned int*)(g),          \
        (__attribute__((address_space(3))) unsigned int*)(l), 16, 0, 0)

// ---------------- fused weight build: Mv (blocks 0..127) + W (128..639) ----------------
__global__ void k_build(const float* __restrict__ logLr, const float* __restrict__ Li_in,
                        const float* __restrict__ logDelta,
                        const float* __restrict__ Br, const float* __restrict__ Bi,
                        const float* __restrict__ Cr, const float* __restrict__ Ci,
                        const float* __restrict__ D,
                        unsigned short* __restrict__ Mv, unsigned short* __restrict__ W) {
    int bid = blockIdx.x;
    if (bid < 128) {
        int np = bid, p = threadIdx.x;
        if (p < DMODEL) {
            int n = np & 63;
            float Delta = expf(logDelta[0]);
            float llr = fminf(fmaxf(logLr[n], -10.f), 10.f);
            float Lr = -expf(llr);
            float Li = Li_in[n];
            float dr = 1.f - 0.5f * Delta * Lr;
            float di = -0.5f * Delta * Li;
            float dn = dr * dr + di * di;
            float sr = Delta * dr / dn;
            float si = -Delta * di / dn;
            float br = Br[n * DMODEL + p], bi = Bi[n * DMODEL + p];
            float v = (np < HALF) ? (sr * br - si * bi) : (si * br + sr * bi);
            Mv[np * DMODEL + p] = f2bf(v);
        }
    } else {
        int p = bid - 128, j = threadIdx.x;
        float v;
        if (j < HALF) v = 2.f * Cr[p * HALF + j];
        else if (j < 2 * HALF) v = -2.f * Ci[p * HALF + (j - HALF)];
        else v = D[p * DMODEL + (j - 2 * HALF)];
        W[p * 640 + j] = f2bf(v);
    }
}

// ---------------- scanA: chunk-end local states E ----------------
__global__ void k_scanA(const unsigned short* __restrict__ Vb,
                        const float* __restrict__ logLr, const float* __restrict__ Li_in,
                        const float* __restrict__ logDelta,
                        float* __restrict__ E) {
    int tid = threadIdx.x;
    int n = tid & 63;
    int c = ((blockIdx.x & 31) << 1) + (tid >> 6);
    int b = blockIdx.x >> 5;
    float Ar, Ai;
    poleA(logLr, Li_in, logDelta, n, Ar, Ai);
    float xr = 0.f, xi = 0.f;
    size_t base = ((size_t)b * SEQ + (size_t)c * CHUNK) * 128 + n;
    for (int tl = 0; tl < CHUNK; ++tl) {
        float vr = bf2f(Vb[base]), vi = bf2f(Vb[base + 64]);
        float nxr = Ar * xr - Ai * xi + vr;
        float nxi = Ar * xi + Ai * xr + vi;
        xr = nxr; xi = nxi;
        base += 128;
    }
    int eidx = ((b * NCHUNK + c) * 2) * HALF + n;
    E[eidx] = xr; E[eidx + 64] = xi;
}

// ---------------- scanCB: direct carry sum + seeded recurrence -> Xb ----------------
__global__ void k_scanCB(const unsigned short* __restrict__ Vb,
                         const float* __restrict__ E,
                         const float* __restrict__ logLr, const float* __restrict__ Li_in,
                         const float* __restrict__ logDelta,
                         unsigned short* __restrict__ Xb) {
    int tid = threadIdx.x;
    int n = tid & 63;
    int c = ((blockIdx.x & 31) << 1) + (tid >> 6);
    int b = blockIdx.x >> 5;
    float Ar, Ai;
    poleA(logLr, Li_in, logDelta, n, Ar, Ai);
    // A^64 by 6 squarings
    float a64r = Ar, a64i = Ai;
#pragma unroll
    for (int s = 0; s < 6; ++s) {
        float t = a64r * a64r - a64i * a64i;
        a64i = 2.f * a64r * a64i;
        a64r = t;
    }
    // carry_c = sum_{jj=1..c} (A^64)^(jj-1) * E_{c-jj}   (exact; E is L2-resident)
    float xr = 0.f, xi = 0.f, wr = 1.f, wi = 0.f;
    for (int jj = 1; jj <= c; ++jj) {
        int ei = ((b * NCHUNK + (c - jj)) * 2) * HALF + n;
        float er = E[ei], ev = E[ei + 64];
        xr += wr * er - wi * ev;
        xi += wr * ev + wi * er;
        float nwr = wr * a64r - wi * a64i;
        float nwi = wr * a64i + wi * a64r;
        wr = nwr; wi = nwi;
    }
    // seeded recurrence over the chunk
    size_t base = ((size_t)b * SEQ + (size_t)c * CHUNK) * 128 + n;
    for (int tl = 0; tl < CHUNK; ++tl) {
        float vr = bf2f(Vb[base]), vi = bf2f(Vb[base + 64]);
        float nxr = Ar * xr - Ai * xi + vr;
        float nxi = Ar * xi + Ai * xr + vi;
        xr = nxr; xi = nxi;
        Xb[base] = f2bf(xr); Xb[base + 64] = f2bf(xi);
        base += 128;
    }
}

// ---------------- GEMM1 (r8 exact): Vb = bf16(U @ Mv^T), Ub = bf16(U) ----------------
__global__ __launch_bounds__(512) void gemm1(const float* __restrict__ U,
                                             const unsigned short* __restrict__ Mv,
                                             unsigned short* __restrict__ Vb,
                                             unsigned short* __restrict__ Ub) {
    __shared__ __align__(16) unsigned short As[64 * 32];
    __shared__ __align__(16) unsigned short Bs[128 * 32];
    const int tid = threadIdx.x;
    const int lane = tid & 63;
    const int w = tid >> 6;            // 0..7
    const int wm = w >> 2, wn = w & 3; // 2 x 4
    const int l15 = lane & 15, l4 = lane >> 4;
    const int row0 = blockIdx.x * 64;
    const int srow = tid >> 3;         // 0..63
    const int sh = (tid & 7) * 4;      // 0..28

    f32x4 acc[2][2];
#pragma unroll
    for (int m = 0; m < 2; ++m)
#pragma unroll
        for (int n = 0; n < 2; ++n) acc[m][n] = (f32x4)(0.f);

    for (int k0 = 0; k0 < DMODEL; k0 += 32) {
        const float4 av = *(const float4*)(U + (size_t)(row0 + srow) * DMODEL + k0 + sh);

        __syncthreads();   // prior tile's LDS reads complete

        GLOAD_LDS16(Mv + (size_t)(tid >> 2) * DMODEL + k0 + (tid & 3) * 8,
                    &Bs[(w * 64) * 8]);

        uint2 wa;
        wa.x = (unsigned)f2bf(av.x) | ((unsigned)f2bf(av.y) << 16);
        wa.y = (unsigned)f2bf(av.z) | ((unsigned)f2bf(av.w) << 16);
        *(uint2*)&As[srow * 32 + sh] = wa;
        *(uint2*)&Ub[(size_t)(row0 + srow) * DMODEL + k0 + sh] = wa;

        __syncthreads();   // vmcnt+lgkm drain: tiles staged

        short8 af[2], bf[2];
#pragma unroll
        for (int m = 0; m < 2; ++m)
            af[m] = *(const short8*)&As[(wm * 32 + m * 16 + l15) * 32 + l4 * 8];
#pragma unroll
        for (int n = 0; n < 2; ++n)
            bf[n] = *(const short8*)&Bs[(wn * 32 + n * 16 + l15) * 32 + l4 * 8];
#pragma unroll
        for (int m = 0; m < 2; ++m)
#pragma unroll
            for (int n = 0; n < 2; ++n)
                acc[m][n] = __builtin_amdgcn_mfma_f32_16x16x32_bf16(af[m], bf[n], acc[m][n], 0, 0, 0);
    }

#pragma unroll
    for (int m = 0; m < 2; ++m) {
        int rbase = row0 + wm * 32 + m * 16 + l4 * 4;
#pragma unroll
        for (int n = 0; n < 2; ++n) {
            int col = wn * 32 + n * 16 + l15;
#pragma unroll
            for (int r = 0; r < 4; ++r)
                Vb[(size_t)(rbase + r) * 128 + col] = f2bf(acc[m][n][r]);
        }
    }
}

// ---------------- GEMM23 (r8 exact): out = [Xb | Ub] @ W^T ----------------
// 256x256, BK=32 per kh-phase, 4-slot ring (slot = (2t+kh)&3 = (t&1)*2+kh),
// prefetch distance 3 kh-phases, counted vmcnt(8); drain ladder 4,0 at tail.

#define STAGE_K(t, kh, j) do {                                                 \
    int c_ = (kh) * 1024 + (j) * 512 + tid;                                    \
    int ct_ = c_ ^ (((c_ >> 5) & 1) << 1);                                     \
    int r_ = (ct_ >> 2) & 255;                                                 \
    int kcol_ = (t) * 64 + (kh) * 32 + (ct_ & 3) * 8;                          \
    const unsigned short* asrc_ = (kcol_ < 128)                                \
        ? Xb + (size_t)(row0 + r_) * 128 + kcol_                               \
        : Ub + (size_t)(row0 + r_) * 512 + (kcol_ - 128);                      \
    GLOAD_LDS16(asrc_, &As[((t) & 1) * 16384 + ((kh) * 1024 + (j) * 512 + w * 64) * 8]); \
    GLOAD_LDS16(W + (size_t)(col0 + r_) * 640 + kcol_,                         \
                &Bs[((t) & 1) * 16384 + ((kh) * 1024 + (j) * 512 + w * 64) * 8]); \
} while (0)

#define LDAB(t, kh) do {                                                       \
    _Pragma("unroll") for (int i_ = 0; i_ < 8; ++i_) {                         \
        int r_ = wm * 128 + i_ * 16 + l15;                                     \
        int c_ = (l4 * 8) ^ (((r_ >> 3) & 1) << 4);                            \
        af[i_] = *(const short8*)&As[((t) & 1) * 16384 + (kh) * 8192 + r_ * 32 + c_]; \
    }                                                                          \
    _Pragma("unroll") for (int j_ = 0; j_ < 4; ++j_) {                         \
        int r_ = wn * 64 + j_ * 16 + l15;                                      \
        int c_ = (l4 * 8) ^ (((r_ >> 3) & 1) << 4);                            \
        bf[j_] = *(const short8*)&Bs[((t) & 1) * 16384 + (kh) * 8192 + r_ * 32 + c_]; \
    } } while (0)

#define MFMA32() do {                                                          \
    __builtin_amdgcn_s_setprio(1);                                             \
    _Pragma("unroll") for (int i_ = 0; i_ < 8; ++i_)                           \
    _Pragma("unroll") for (int j_ = 0; j_ < 4; ++j_)                           \
        acc[i_][j_] = __builtin_amdgcn_mfma_f32_16x16x32_bf16(                 \
            af[i_], bf[j_], acc[i_][j_], 0, 0, 0);                             \
    __builtin_amdgcn_s_setprio(0);                                             \
} while (0)

#define PHASE_SYNC(N) do {                                                     \
    asm volatile("s_waitcnt vmcnt(" #N ")" ::: "memory");                      \
    __builtin_amdgcn_s_barrier();                                              \
    __builtin_amdgcn_sched_barrier(0);                                         \
} while (0)

__global__ __launch_bounds__(512) void gemm23_8p(const unsigned short* __restrict__ Xb,
                                                 const unsigned short* __restrict__ Ub,
                                                 const unsigned short* __restrict__ W,
                                                 float* __restrict__ C) {
    __shared__ __align__(16) unsigned short As[2 * 16384];  // 64 KiB = 4 kh-slots
    __shared__ __align__(16) unsigned short Bs[2 * 16384];  // 64 KiB
    const int tid = threadIdx.x;
    const int lane = tid & 63;
    const int w = tid >> 6;             // 0..7
    const int wm = w >> 2, wn = w & 3;  // 2 x 4
    const int l15 = lane & 15, l4 = lane >> 4;

    // T1: bijective XCD swizzle over 256 blocks
    int lin = blockIdx.y * gridDim.x + blockIdx.x;  // 0..255
    int sw = (lin & 7) * 32 + (lin >> 3);
    const int row0 = (sw & 127) * 256;
    const int col0 = (sw >> 7) * 256;

    f32x4 acc[8][4];
#pragma unroll
    for (int m = 0; m < 8; ++m)
#pragma unroll
        for (int n = 0; n < 4; ++n) acc[m][n] = (f32x4)(0.f);

    // prologue: stage kh-phases 0,1,2 (12 loads/thread in flight)
    STAGE_K(0, 0, 0); STAGE_K(0, 0, 1);
    STAGE_K(0, 1, 0); STAGE_K(0, 1, 1);
    STAGE_K(1, 0, 0); STAGE_K(1, 0, 1);

    short8 af[8], bf[4];
    for (int t = 0; t < NT - 1; ++t) {   // t = 0..8
        // phase A (p = 2t): consume kh0, stage kh_{2t+3} = (t+1, kh1)
        PHASE_SYNC(8);
        LDAB(t, 0);
        STAGE_K(t + 1, 1, 0); STAGE_K(t + 1, 1, 1);
        MFMA32();
        // phase B (p = 2t+1): consume kh1, stage kh_{2t+4} = (t+2, kh0)
        PHASE_SYNC(8);
        LDAB(t, 1);
        if (t < NT - 2) { STAGE_K(t + 2, 0, 0); STAGE_K(t + 2, 0, 1); }
        MFMA32();
    }
    // tail t = NT-1: phases 18 (vmcnt 4) and 19 (vmcnt 0)
    PHASE_SYNC(4);
    LDAB(NT - 1, 0);
    MFMA32();
    PHASE_SYNC(0);
    LDAB(NT - 1, 1);
    MFMA32();

#pragma unroll
    for (int m = 0; m < 8; ++m) {
        int rbase = row0 + wm * 128 + m * 16 + l4 * 4;
#pragma unroll
        for (int n = 0; n < 4; ++n) {
            int col = col0 + wn * 64 + n * 16 + l15;
#pragma unroll
            for (int r = 0; r < 4; ++r)
                C[(size_t)(rbase + r) * DMODEL + col] = acc[m][n][r];
        }
    }
}

// ---------------- launch ----------------

extern "C" void kernel_launch(void* const* d_in, const int* in_sizes, int n_in,
                              void* d_out, int out_size, void* d_ws, size_t ws_size,
                              hipStream_t stream) {
    const float* u      = (const float*)d_in[0];
    const float* logLr  = (const float*)d_in[1];
    const float* Li     = (const float*)d_in[2];
    const float* Br     = (const float*)d_in[3];
    const float* Bi     = (const float*)d_in[4];
    const float* Cr     = (const float*)d_in[5];
    const float* Ci     = (const float*)d_in[6];
    const float* D      = (const float*)d_in[7];
    const float* logDel = (const float*)d_in[8];
    float* out = (float*)d_out;

    const size_t M = (size_t)BATCH * SEQ;  // 32768
    unsigned short* Vb = (unsigned short*)d_ws;       // M*128
    unsigned short* Ub = Vb + M * 128;                // M*512
    unsigned short* Xb = Ub + M * 512;                // M*128
    unsigned short* Mv = Xb + M * 128;                // 128*512
    unsigned short* W  = Mv + 128 * 512;              // 512*640
    float* E     = (float*)(W + 512 * 640);           // 65536

    // fused weight build (Mv + W)
    hipLaunchKernelGGL(k_build, dim3(640), dim3(640), 0, stream,
                       logLr, Li, logDel, Br, Bi, Cr, Ci, D, Mv, W);

    // GEMM1: Vb = bf16(U @ Mv^T), Ub = bf16(U)
    hipLaunchKernelGGL(gemm1, dim3(M / 64), dim3(512), 0, stream, u, Mv, Vb, Ub);

    // scan: chunk-end states -> fused exact carry + seeded recurrence -> Xb
    hipLaunchKernelGGL(k_scanA, dim3(256), dim3(128), 0, stream,
                       Vb, logLr, Li, logDel, E);
    hipLaunchKernelGGL(k_scanCB, dim3(256), dim3(128), 0, stream,
                       Vb, E, logLr, Li, logDel, Xb);

    // GEMM23: out = [Xb | Ub] @ W^T
    hipLaunchKernelGGL(gemm23_8p, dim3(M / 256, DMODEL / 256), dim3(512), 0, stream,
                       Xb, Ub, W, out);
}